// Round 5
// baseline (6338.526 us; speedup 1.0000x reference)
//
#include <hip/hip_runtime.h>

#define S_LEN 8192
#define DIN 120
#define HID 64
#define G4 256
#define NOUT 10
#define DHPM 258

typedef _Float16 half8 __attribute__((ext_vector_type(8)));
typedef float f32x4 __attribute__((ext_vector_type(4)));
#define MFMA16(a, b, c) __builtin_amdgcn_mfma_f32_16x16x32_f16((a), (b), (c), 0, 0, 0)

// ---------------- workspace layout (float offsets) ----------------
// PRE0 is UNIT-MAJOR: [S][unit 0..63][gate i,f,g,o]
static constexpr size_t OFF_PRE0 = 0;                                  // [S][64][4]
static constexpr size_t OFF_ACT0 = OFF_PRE0 + (size_t)S_LEN * G4;      // [S][256] activated gates L0 (row = grp*64+unit)
static constexpr size_t OFF_ACT1 = OFF_ACT0 + (size_t)S_LEN * G4;      // [S][256] activated gates L1
static constexpr size_t OFF_H0S  = OFF_ACT1 + (size_t)S_LEN * G4;      // [S+1][64]  row t+1 = h0 after step t, row0 = 0
static constexpr size_t OFF_C0S  = OFF_H0S + (size_t)(S_LEN + 1) * HID;
static constexpr size_t OFF_H1S  = OFF_C0S + (size_t)(S_LEN + 1) * HID; // [S+2][64] row t+2 = h1 after step t
static constexpr size_t OFF_C1S  = OFF_H1S + (size_t)(S_LEN + 2) * HID;
static constexpr size_t OFF_GOH  = OFF_C1S + (size_t)(S_LEN + 2) * HID; // [S][64]
static constexpr size_t OFF_GWS  = OFF_GOH + (size_t)S_LEN * HID;       // [S][120]
static constexpr size_t OFF_PMN  = OFF_GWS + (size_t)S_LEN * DIN;       // [2][64][64]
static constexpr size_t OFF_PMX  = OFF_PMN + 2 * 64 * 64;
static constexpr size_t OFF_MN   = OFF_PMX + 2 * 64 * 64;               // [2][64]
static constexpr size_t OFF_INV  = OFF_MN + 128;                        // [2][64]
static constexpr size_t OFF_WSUM = OFF_INV + 128;                       // [64]
static constexpr size_t OFF_S2   = OFF_WSUM + 64;                       // [2]

__device__ __forceinline__ float sig_(float x)  { return 1.0f / (1.0f + __expf(-x)); }
__device__ __forceinline__ float tanh_(float x) { return 1.0f - 2.0f / (__expf(2.0f * x) + 1.0f); }

// load 8 consecutive f32 weights W[row][k0..k0+8), convert to a f16 fragment
__device__ __forceinline__ half8 ldw_(const float* __restrict__ Wp, int row, int k0) {
  const float4* p = (const float4*)(Wp + (size_t)row * HID + k0);
  float4 x = p[0], y = p[1];
  half8 h;
  h[0] = (_Float16)x.x; h[1] = (_Float16)x.y; h[2] = (_Float16)x.z; h[3] = (_Float16)x.w;
  h[4] = (_Float16)y.x; h[5] = (_Float16)y.y; h[6] = (_Float16)y.z; h[7] = (_Float16)y.w;
  return h;
}

// ---------------- prep: wsum = colsum(Wlin), s2 = colsum(Whpm2) ----------------
__global__ __launch_bounds__(128) void wl_prep_kernel(const float* __restrict__ Wlin,
                                                      const float* __restrict__ Whpm2,
                                                      float* __restrict__ ws) {
  int i = threadIdx.x;
  if (i < HID) {
    float s = 0.0f;
    for (int o = 0; o < NOUT; ++o) s += Wlin[o * HID + i];
    ws[OFF_WSUM + i] = s;
  } else if (i < HID + 2) {
    int h = i - HID;
    float s = 0.0f;
    for (int d = 0; d < DIN; ++d) s += Whpm2[d * 2 + h];
    ws[OFF_S2 + h] = s;
  }
}

// ---------------- pre0 = input @ Wih0.T + bih0 + bhh0, UNIT-MAJOR output ----------------
__global__ __launch_bounds__(256) void wl_pre0_kernel(const float* __restrict__ input,
                                                      const float* __restrict__ Wih0,
                                                      const float* __restrict__ bih0,
                                                      const float* __restrict__ bhh0,
                                                      float* __restrict__ ws) {
  __shared__ __align__(16) float xin[8 * DIN];
  int tid = threadIdx.x;
  int grp = tid >> 6, un = tid & 63;
  size_t t0 = (size_t)blockIdx.x * 8;
  for (int idx = tid; idx < 8 * DIN; idx += 256) xin[idx] = input[t0 * DIN + idx];
  float4 w[30];
  const float4* wr = (const float4*)(Wih0 + (size_t)tid * DIN);
#pragma unroll
  for (int i = 0; i < 30; ++i) w[i] = wr[i];
  float b = bih0[tid] + bhh0[tid];
  __syncthreads();
#pragma unroll
  for (int tt = 0; tt < 8; ++tt) {
    const float4* x4 = (const float4*)(xin + tt * DIN);
    float acc = b;
#pragma unroll
    for (int i = 0; i < 30; ++i) {
      float4 x = x4[i];
      acc += w[i].x * x.x + w[i].y * x.y + w[i].z * x.z + w[i].w * x.w;
    }
    ws[OFF_PRE0 + (t0 + tt) * G4 + un * 4 + grp] = acc;  // unit-major
  }
}

// ---------------- sequential scan: MFMA matvec, one barrier per step ----------------
// 512 thr / 8 waves. Waves 0-3: layer0 (wave w owns units 16w..16w+16).
// Waves 4-7: layer1, lagging one superstep. Matvec gates = h @ W^T as MFMA:
// A row 0 = h (f16, from 128B LDS buffer, 1 ds_read_b128 per K-half),
// B = 16 weight rows of gate-type g for this wave's units (register-resident).
// C: lane u<16, reg 0 = gate g of unit 16w+u -> cell update fully lane-local.
__global__ __launch_bounds__(512, 2) void wl_scan_kernel(const float* __restrict__ Whh0,
                                                         const float* __restrict__ Wih1,
                                                         const float* __restrict__ Whh1,
                                                         const float* __restrict__ bih1,
                                                         const float* __restrict__ bhh1,
                                                         float* __restrict__ ws) {
  __shared__ __align__(16) _Float16 h0h[2][HID];  // [buf][unit]
  __shared__ __align__(16) _Float16 h1h[2][HID];
  float* ACT0 = ws + OFF_ACT0;
  float* ACT1 = ws + OFF_ACT1;
  float* H0S = ws + OFF_H0S;
  float* C0S = ws + OFF_C0S;
  float* H1S = ws + OFF_H1S;
  float* C1S = ws + OFF_C1S;
  const float* PRE0 = ws + OFF_PRE0;

  int tid = threadIdx.x;
  int wv = tid >> 6;
  int lane = tid & 63;
  int urow = lane & 15;   // B-fragment: row-within-tile (weight row selector)
  int kq = lane >> 4;     // k-chunk 0..3
  bool isL1 = (wv >= 4);
  int w = wv & 3;         // wave-in-layer
  int gu = 16 * w + urow; // this lane's unit (meaningful for lane<16)

  // B-fragments: wfA = Whh0 (L0) or Wih1 (L1); wfB = Whh1 (L1 only)
  const float* WAp = isL1 ? Wih1 : Whh0;
  half8 wfA[4][2], wfB[4][2];
#pragma unroll
  for (int g = 0; g < 4; ++g) {
#pragma unroll
    for (int kh = 0; kh < 2; ++kh) {
      wfA[g][kh] = ldw_(WAp, g * 64 + 16 * w + urow, kh * 32 + kq * 8);
      if (isL1) wfB[g][kh] = ldw_(Whh1, g * 64 + 16 * w + urow, kh * 32 + kq * 8);
      else      wfB[g][kh] = half8{};
    }
  }
  // L1 bias (i,f,g,o of unit gu), valid for lanes<16
  float4 b1v;
  b1v.x = bih1[gu] + bhh1[gu];
  b1v.y = bih1[64 + gu] + bhh1[64 + gu];
  b1v.z = bih1[128 + gu] + bhh1[128 + gu];
  b1v.w = bih1[192 + gu] + bhh1[192 + gu];

  // init LDS h buffers and boundary rows of the global state arrays
  if (tid < 128) {
    ((_Float16*)h0h)[tid] = (_Float16)0;
    ((_Float16*)h1h)[tid] = (_Float16)0;
  }
  if (tid < HID) {
    H0S[tid] = 0.0f; C0S[tid] = 0.0f;
    H1S[tid] = 0.0f; H1S[HID + tid] = 0.0f;
    C1S[tid] = 0.0f; C1S[HID + tid] = 0.0f;
  }
  float cc = 0.0f;
  float4 pre_cur = *(const float4*)(PRE0 + (size_t)0 * G4 + gu * 4);
  __syncthreads();

  const f32x4 zed = {0.f, 0.f, 0.f, 0.f};
  for (int s = 0; s <= S_LEN; ++s) {
    int rb = s & 1, wb = rb ^ 1;
    if (!isL1) {
      if (s < S_LEN) {
        const half8* hb = (const half8*)h0h[rb];
        half8 a0 = hb[kq];        // k = kq*8 .. +8      (K-half 0)
        half8 a1 = hb[4 + kq];    // k = 32 + kq*8 .. +8 (K-half 1)
        f32x4 ai = MFMA16(a0, wfA[0][0], zed); ai = MFMA16(a1, wfA[0][1], ai);
        f32x4 af = MFMA16(a0, wfA[1][0], zed); af = MFMA16(a1, wfA[1][1], af);
        f32x4 ag = MFMA16(a0, wfA[2][0], zed); ag = MFMA16(a1, wfA[2][1], ag);
        f32x4 ao = MFMA16(a0, wfA[3][0], zed); ao = MFMA16(a1, wfA[3][1], ao);
        float4 pr = pre_cur;
        if (s + 1 < S_LEN) pre_cur = *(const float4*)(PRE0 + (size_t)(s + 1) * G4 + gu * 4);
        if (lane < 16) {
          float gi = sig_(ai[0] + pr.x);
          float gf = sig_(af[0] + pr.y);
          float gg = tanh_(ag[0] + pr.z);
          float go = sig_(ao[0] + pr.w);
          cc = gf * cc + gi * gg;
          float th = tanh_(cc);
          float h = go * th;
          ACT0[(size_t)s * G4 + gu] = gi;
          ACT0[(size_t)s * G4 + 64 + gu] = gf;
          ACT0[(size_t)s * G4 + 128 + gu] = gg;
          ACT0[(size_t)s * G4 + 192 + gu] = go;
          H0S[(size_t)(s + 1) * HID + gu] = h;
          C0S[(size_t)(s + 1) * HID + gu] = cc;
          h0h[wb][gu] = (_Float16)h;
        }
      }
    } else {
      if (s >= 1) {
        int t = s - 1;
        const half8* hb0 = (const half8*)h0h[rb];  // h0[t]
        const half8* hb1 = (const half8*)h1h[rb];  // h1[t-1]
        half8 a00 = hb0[kq], a01 = hb0[4 + kq];
        half8 a10 = hb1[kq], a11 = hb1[4 + kq];
        f32x4 ai = MFMA16(a00, wfA[0][0], zed); ai = MFMA16(a01, wfA[0][1], ai);
        ai = MFMA16(a10, wfB[0][0], ai); ai = MFMA16(a11, wfB[0][1], ai);
        f32x4 af = MFMA16(a00, wfA[1][0], zed); af = MFMA16(a01, wfA[1][1], af);
        af = MFMA16(a10, wfB[1][0], af); af = MFMA16(a11, wfB[1][1], af);
        f32x4 ag = MFMA16(a00, wfA[2][0], zed); ag = MFMA16(a01, wfA[2][1], ag);
        ag = MFMA16(a10, wfB[2][0], ag); ag = MFMA16(a11, wfB[2][1], ag);
        f32x4 ao = MFMA16(a00, wfA[3][0], zed); ao = MFMA16(a01, wfA[3][1], ao);
        ao = MFMA16(a10, wfB[3][0], ao); ao = MFMA16(a11, wfB[3][1], ao);
        if (lane < 16) {
          float gi = sig_(ai[0] + b1v.x);
          float gf = sig_(af[0] + b1v.y);
          float gg = tanh_(ag[0] + b1v.z);
          float go = sig_(ao[0] + b1v.w);
          cc = gf * cc + gi * gg;
          float th = tanh_(cc);
          float h = go * th;
          ACT1[(size_t)t * G4 + gu] = gi;
          ACT1[(size_t)t * G4 + 64 + gu] = gf;
          ACT1[(size_t)t * G4 + 128 + gu] = gg;
          ACT1[(size_t)t * G4 + 192 + gu] = go;
          H1S[(size_t)(t + 2) * HID + gu] = h;
          C1S[(size_t)(t + 2) * HID + gu] = cc;
          h1h[wb][gu] = (_Float16)h;
        }
      }
    }
    // one barrier per superstep; LDS drained, global stores fire-and-forget
    asm volatile("s_waitcnt lgkmcnt(0)" ::: "memory");
    __builtin_amdgcn_sched_barrier(0);
    __builtin_amdgcn_s_barrier();
    __builtin_amdgcn_sched_barrier(0);
  }
}

// ---------------- per-t gradient (fully parallel; uses stored activations only) ----------------
__global__ __launch_bounds__(256) void wl_grad_kernel(const float* __restrict__ Wih0,
                                                      const float* __restrict__ Whh0,
                                                      const float* __restrict__ Wih1,
                                                      const float* __restrict__ Whh1,
                                                      float* __restrict__ ws) {
  int t = blockIdx.x;
  int tid = threadIdx.x;
  float* GOH = ws + OFF_GOH;
  float* GWS = ws + OFF_GWS;
  if (t == 0) {  // gohs[0]=0, gws[0]=0
    if (tid < HID) GOH[tid] = 0.0f;
    if (tid < DIN) GWS[tid] = 0.0f;
    return;
  }
  const float* ACT0 = ws + OFF_ACT0;
  const float* ACT1 = ws + OFF_ACT1;
  const float* C0S = ws + OFF_C0S;
  const float* C1S = ws + OFF_C1S;
  __shared__ float a3[G4], am[G4], a0[G4];
  __shared__ float dg3[G4], dg0[G4], dgm[G4];
  __shared__ float dh0n[HID], dh1m[HID], dc1m[HID];
  __shared__ float cbuf[5 * HID];  // c3 | c1m | c1pp | c0n | c0p
  __shared__ float wsum_s[HID];
  a3[tid] = ACT1[(size_t)t * G4 + tid];
  am[tid] = ACT1[(size_t)(t - 1) * G4 + tid];
  a0[tid] = ACT0[(size_t)t * G4 + tid];
  if (tid < HID) {
    cbuf[tid]           = C1S[(size_t)(t + 2) * HID + tid];  // c3  = c1[t]
    cbuf[HID + tid]     = C1S[(size_t)(t + 1) * HID + tid];  // c1m = c1[t-1]
    cbuf[2 * HID + tid] = C1S[(size_t)t * HID + tid];        // c1pp= c1[t-2]
    cbuf[3 * HID + tid] = C0S[(size_t)(t + 1) * HID + tid];  // c0n = c0[t]
    cbuf[4 * HID + tid] = C0S[(size_t)t * HID + tid];        // c0p = c0[t-1]
    wsum_s[tid] = ws[OFF_WSUM + tid];
  }
  __syncthreads();
  // backward through cell3 (== real layer-1 cell at step t)
  if (tid < HID) {
    int k = tid;
    float tc = tanh_(cbuf[k]);
    float si = a3[k], sf = a3[HID + k], tg = a3[2 * HID + k], so = a3[3 * HID + k];
    float dh = wsum_s[k];
    float dov = dh * tc * so * (1.0f - so);
    float dc = dh * so * (1.0f - tc * tc);
    dg3[k] = dc * tg * si * (1.0f - si);
    dg3[HID + k] = dc * cbuf[HID + k] * sf * (1.0f - sf);
    dg3[2 * HID + k] = dc * si * (1.0f - tg * tg);
    dg3[3 * HID + k] = dov;
    dc1m[k] = dc * sf;
  }
  __syncthreads();
  // dh0n = dg3 @ Wih1 ; dh1m = dg3 @ Whh1
  if (tid < HID) {
    float s = 0.0f;
#pragma unroll 8
    for (int j = 0; j < G4; ++j) s += dg3[j] * Wih1[(size_t)j * HID + tid];
    dh0n[tid] = s;
  } else if (tid < 2 * HID) {
    int k = tid - HID;
    float s = 0.0f;
#pragma unroll 8
    for (int j = 0; j < G4; ++j) s += dg3[j] * Whh1[(size_t)j * HID + k];
    dh1m[k] = s;
  }
  __syncthreads();
  // backward through cell0 (dc0n = 0) and cellm (== layer-1 cell at step t-1)
  if (tid < HID) {
    int k = tid;
    float tc = tanh_(cbuf[3 * HID + k]);
    float si = a0[k], sf = a0[HID + k], tg = a0[2 * HID + k], so = a0[3 * HID + k];
    float dh = dh0n[k];
    float dov = dh * tc * so * (1.0f - so);
    float dc = dh * so * (1.0f - tc * tc);
    dg0[k] = dc * tg * si * (1.0f - si);
    dg0[HID + k] = dc * cbuf[4 * HID + k] * sf * (1.0f - sf);
    dg0[2 * HID + k] = dc * si * (1.0f - tg * tg);
    dg0[3 * HID + k] = dov;
  } else if (tid < 2 * HID) {
    int k = tid - HID;
    float tc = tanh_(cbuf[HID + k]);
    float si = am[k], sf = am[HID + k], tg = am[2 * HID + k], so = am[3 * HID + k];
    float dh = dh1m[k];
    float dov = dh * tc * so * (1.0f - so);
    float dc = dh * so * (1.0f - tc * tc) + dc1m[k];
    dgm[k] = dc * tg * si * (1.0f - si);
    dgm[HID + k] = dc * cbuf[2 * HID + k] * sf * (1.0f - sf);
    dgm[2 * HID + k] = dc * si * (1.0f - tg * tg);
    dgm[3 * HID + k] = dov;
  }
  __syncthreads();
  // gws = dg0 @ Wih0 ; gohs = dg0 @ Whh0 + dgm @ Wih1
  if (tid < DIN) {
    float s = 0.0f;
#pragma unroll 8
    for (int j = 0; j < G4; ++j) s += dg0[j] * Wih0[(size_t)j * DIN + tid];
    GWS[(size_t)t * DIN + tid] = s;
  } else if (tid < DIN + HID) {
    int k = tid - DIN;
    float sA = 0.0f, sB = 0.0f;
#pragma unroll 8
    for (int j = 0; j < G4; ++j) {
      sA += dg0[j] * Whh0[(size_t)j * HID + k];
      sB += dgm[j] * Wih1[(size_t)j * HID + k];
    }
    GOH[(size_t)t * HID + k] = sA + sB;
  }
}

// ---------------- outs[t] = Wlin @ h1[t] + blin ----------------
__global__ __launch_bounds__(256) void wl_outs_kernel(const float* __restrict__ Wlin,
                                                      const float* __restrict__ blin,
                                                      const float* __restrict__ ws,
                                                      float* __restrict__ out) {
  int tloc = threadIdx.x >> 5, o = threadIdx.x & 31;
  int t = blockIdx.x * 8 + tloc;
  if (o < NOUT) {
    const float* h1 = ws + OFF_H1S + (size_t)(t + 2) * HID;
    const float* wr = Wlin + o * HID;
    float s = blin[o];
#pragma unroll 8
    for (int k = 0; k < HID; ++k) s += wr[k] * h1[k];
    out[(size_t)t * NOUT + o] = s;
  }
}

// ---------------- column-wise min/max partials for gohs (m=0) and old_hts (m=1) ----------------
__global__ __launch_bounds__(256) void wl_mm_partial_kernel(float* __restrict__ ws) {
  int m = blockIdx.y;
  int col = threadIdx.x & 63, rg = threadIdx.x >> 6;
  const float* src = ws + (m == 0 ? OFF_GOH : OFF_H0S);  // H0S rows 0..8191 == old_hts
  float mn = 3.4e38f, mx = -3.4e38f;
  int r0 = blockIdx.x * 128;
  for (int r = r0 + rg; r < r0 + 128; r += 4) {
    float v = src[(size_t)r * HID + col];
    mn = fminf(mn, v);
    mx = fmaxf(mx, v);
  }
  __shared__ float smn[256], smx[256];
  smn[threadIdx.x] = mn;
  smx[threadIdx.x] = mx;
  __syncthreads();
  if (threadIdx.x < 64) {
    float a = fminf(fminf(smn[col], smn[64 + col]), fminf(smn[128 + col], smn[192 + col]));
    float b = fmaxf(fmaxf(smx[col], smx[64 + col]), fmaxf(smx[128 + col], smx[192 + col]));
    ws[OFF_PMN + ((size_t)m * 64 + blockIdx.x) * 64 + col] = a;
    ws[OFF_PMX + ((size_t)m * 64 + blockIdx.x) * 64 + col] = b;
  }
}

__global__ __launch_bounds__(128) void wl_mm_final_kernel(float* __restrict__ ws) {
  int i = threadIdx.x;
  if (i < 128) {
    int m = i >> 6, col = i & 63;
    float mn = 3.4e38f, mx = -3.4e38f;
    for (int b = 0; b < 64; ++b) {
      mn = fminf(mn, ws[OFF_PMN + ((size_t)m * 64 + b) * 64 + col]);
      mx = fmaxf(mx, ws[OFF_PMX + ((size_t)m * 64 + b) * 64 + col]);
    }
    ws[OFF_MN + i] = mn;
    ws[OFF_INV + i] = 1.0f / (mx - mn + 1e-6f);
  }
}

// ---------------- final: output_data assembly + HPM fwd + F + AllF_x ----------------
__global__ __launch_bounds__(256) void wl_final_kernel(const float* __restrict__ input,
                                                       const float* __restrict__ Whpm1,
                                                       const float* __restrict__ bhpm1,
                                                       const float* __restrict__ Whpm2,
                                                       const float* __restrict__ bhpm2,
                                                       const float* __restrict__ ws,
                                                       float* __restrict__ out) {
  int t = blockIdx.x;
  int tid = threadIdx.x;
  __shared__ float od[DHPM];
  __shared__ float red[256];
  __shared__ float zb[4];
  const float* GOH = ws + OFF_GOH;
  const float* H0S = ws + OFF_H0S;
  const float* MNp = ws + OFF_MN;
  const float* INVp = ws + OFF_INV;
  if (tid < NOUT) {
    od[tid] = out[(size_t)t * NOUT + tid];
  } else if (tid < 74) {
    int k = tid - 10;
    od[tid] = (GOH[(size_t)t * HID + k] - MNp[k]) * INVp[k];
  } else if (tid < 194) {
    int q = tid - 74;
    od[tid] = input[(size_t)t * DIN + q];
  } else {
    int k = tid - 194;
    od[tid] = (H0S[(size_t)t * HID + k] - MNp[64 + k]) * INVp[64 + k];
  }
  if (tid < 2) {
    int k = 62 + tid;
    od[256 + tid] = (H0S[(size_t)t * HID + k] - MNp[64 + k]) * INVp[64 + k];
  }
  __syncthreads();
  // z1pre[0]
  float p = od[tid] * Whpm1[tid];
  if (tid < 2) p += od[256 + tid] * Whpm1[256 + tid];
  red[tid] = p;
  __syncthreads();
  for (int off = 128; off > 0; off >>= 1) {
    if (tid < off) red[tid] += red[tid + off];
    __syncthreads();
  }
  if (tid == 0) zb[0] = red[0];
  __syncthreads();
  // z1pre[1]
  p = od[tid] * Whpm1[DHPM + tid];
  if (tid < 2) p += od[256 + tid] * Whpm1[DHPM + 256 + tid];
  red[tid] = p;
  __syncthreads();
  for (int off = 128; off > 0; off >>= 1) {
    if (tid < off) red[tid] += red[tid + off];
    __syncthreads();
  }
  if (tid == 0) {
    float z0 = tanh_(zb[0] + bhpm1[0]);
    float z1 = tanh_(red[0] + bhpm1[1]);
    zb[0] = z0;
    zb[1] = z1;
    zb[2] = ws[OFF_S2 + 0] * (1.0f - z0 * z0);
    zb[3] = ws[OFF_S2 + 1] * (1.0f - z1 * z1);
  }
  __syncthreads();
  float z0 = zb[0], z1 = zb[1], d0 = zb[2], d1 = zb[3];
  if (tid < DIN) {
    float G = bhpm2[tid] + z0 * Whpm2[tid * 2] + z1 * Whpm2[tid * 2 + 1];
    out[(size_t)S_LEN * NOUT + (size_t)t * DIN + tid] = ws[OFF_GWS + (size_t)t * DIN + tid] - G;
  }
  out[(size_t)S_LEN * (NOUT + DIN) + (size_t)t * DHPM + tid] = -(d0 * Whpm1[tid] + d1 * Whpm1[DHPM + tid]);
  if (tid < 2) {
    int i2 = 256 + tid;
    out[(size_t)S_LEN * (NOUT + DIN) + (size_t)t * DHPM + i2] = -(d0 * Whpm1[i2] + d1 * Whpm1[DHPM + i2]);
  }
}

extern "C" void kernel_launch(void* const* d_in, const int* in_sizes, int n_in,
                              void* d_out, int out_size, void* d_ws, size_t ws_size,
                              hipStream_t stream) {
  const float* input = (const float*)d_in[0];
  const float* Wih0 = (const float*)d_in[1];
  const float* Whh0 = (const float*)d_in[2];
  const float* bih0 = (const float*)d_in[3];
  const float* bhh0 = (const float*)d_in[4];
  const float* Wih1 = (const float*)d_in[5];
  const float* Whh1 = (const float*)d_in[6];
  const float* bih1 = (const float*)d_in[7];
  const float* bhh1 = (const float*)d_in[8];
  const float* Wlin = (const float*)d_in[9];
  const float* blin = (const float*)d_in[10];
  const float* Whpm1 = (const float*)d_in[11];
  const float* bhpm1 = (const float*)d_in[12];
  const float* Whpm2 = (const float*)d_in[13];
  const float* bhpm2 = (const float*)d_in[14];
  float* ws = (float*)d_ws;
  float* out = (float*)d_out;

  wl_prep_kernel<<<1, 128, 0, stream>>>(Wlin, Whpm2, ws);
  wl_pre0_kernel<<<S_LEN / 8, 256, 0, stream>>>(input, Wih0, bih0, bhh0, ws);
  wl_scan_kernel<<<1, 512, 0, stream>>>(Whh0, Wih1, Whh1, bih1, bhh1, ws);
  wl_grad_kernel<<<S_LEN, 256, 0, stream>>>(Wih0, Whh0, Wih1, Whh1, ws);
  wl_outs_kernel<<<S_LEN / 8, 256, 0, stream>>>(Wlin, blin, ws, out);
  wl_mm_partial_kernel<<<dim3(64, 2), 256, 0, stream>>>(ws);
  wl_mm_final_kernel<<<1, 128, 0, stream>>>(ws);
  wl_final_kernel<<<S_LEN, 256, 0, stream>>>(input, Whpm1, bhpm1, Whpm2, bhpm2, ws, out);
}

// Round 6
// 5634.405 us; speedup vs baseline: 1.1250x; 1.1250x over previous
//
#include <hip/hip_runtime.h>

#define S_LEN 8192
#define DIN 120
#define HID 64
#define G4 256
#define NOUT 10
#define DHPM 258
#define NBLK (S_LEN / 16)

typedef _Float16 half8 __attribute__((ext_vector_type(8)));
typedef float f32x4 __attribute__((ext_vector_type(4)));
#define MFMA16(a, b, c) __builtin_amdgcn_mfma_f32_16x16x32_f16((a), (b), (c), 0, 0, 0)

// ---------------- workspace layout (float offsets) ----------------
// PRE0 is UNIT-MAJOR: [S][unit 0..63][gate i,f,g,o]
static constexpr size_t OFF_PRE0 = 0;                                  // [S][64][4]
static constexpr size_t OFF_ACT0 = OFF_PRE0 + (size_t)S_LEN * G4;      // [S][256] activated gates L0 (row = grp*64+unit)
static constexpr size_t OFF_ACT1 = OFF_ACT0 + (size_t)S_LEN * G4;      // [S][256] activated gates L1
static constexpr size_t OFF_H0S  = OFF_ACT1 + (size_t)S_LEN * G4;      // [S+1][64]  row t+1 = h0 after step t, row0 = 0
static constexpr size_t OFF_C0S  = OFF_H0S + (size_t)(S_LEN + 1) * HID;
static constexpr size_t OFF_H1S  = OFF_C0S + (size_t)(S_LEN + 1) * HID; // [S+2][64] row t+2 = h1 after step t
static constexpr size_t OFF_C1S  = OFF_H1S + (size_t)(S_LEN + 2) * HID;
static constexpr size_t OFF_GOH  = OFF_C1S + (size_t)(S_LEN + 2) * HID; // [S][64]
static constexpr size_t OFF_GWS  = OFF_GOH + (size_t)S_LEN * HID;       // [S][120]
static constexpr size_t OFF_PMN  = OFF_GWS + (size_t)S_LEN * DIN;       // [2][64][64]
static constexpr size_t OFF_PMX  = OFF_PMN + 2 * 64 * 64;
static constexpr size_t OFF_MN   = OFF_PMX + 2 * 64 * 64;               // [2][64]
static constexpr size_t OFF_INV  = OFF_MN + 128;                        // [2][64]
static constexpr size_t OFF_WSUM = OFF_INV + 128;                       // [64]
static constexpr size_t OFF_S2   = OFF_WSUM + 64;                       // [2]

__device__ __forceinline__ float sig_(float x)  { return 1.0f / (1.0f + __expf(-x)); }
__device__ __forceinline__ float tanh_(float x) { return 1.0f - 2.0f / (__expf(2.0f * x) + 1.0f); }

// load 8 consecutive f32 weights W[row][k0..k0+8), convert to a f16 fragment
__device__ __forceinline__ half8 ldw_(const float* __restrict__ Wp, int row, int k0) {
  const float4* p = (const float4*)(Wp + (size_t)row * HID + k0);
  float4 x = p[0], y = p[1];
  half8 h;
  h[0] = (_Float16)x.x; h[1] = (_Float16)x.y; h[2] = (_Float16)x.z; h[3] = (_Float16)x.w;
  h[4] = (_Float16)y.x; h[5] = (_Float16)y.y; h[6] = (_Float16)y.z; h[7] = (_Float16)y.w;
  return h;
}

// ---------------- prep: wsum = colsum(Wlin), s2 = colsum(Whpm2) ----------------
__global__ __launch_bounds__(128) void wl_prep_kernel(const float* __restrict__ Wlin,
                                                      const float* __restrict__ Whpm2,
                                                      float* __restrict__ ws) {
  int i = threadIdx.x;
  if (i < HID) {
    float s = 0.0f;
    for (int o = 0; o < NOUT; ++o) s += Wlin[o * HID + i];
    ws[OFF_WSUM + i] = s;
  } else if (i < HID + 2) {
    int h = i - HID;
    float s = 0.0f;
    for (int d = 0; d < DIN; ++d) s += Whpm2[d * 2 + h];
    ws[OFF_S2 + h] = s;
  }
}

// ---------------- pre0 = input @ Wih0.T + bih0 + bhh0, UNIT-MAJOR output ----------------
__global__ __launch_bounds__(256) void wl_pre0_kernel(const float* __restrict__ input,
                                                      const float* __restrict__ Wih0,
                                                      const float* __restrict__ bih0,
                                                      const float* __restrict__ bhh0,
                                                      float* __restrict__ ws) {
  __shared__ __align__(16) float xin[8 * DIN];
  int tid = threadIdx.x;
  int grp = tid >> 6, un = tid & 63;
  size_t t0 = (size_t)blockIdx.x * 8;
  for (int idx = tid; idx < 8 * DIN; idx += 256) xin[idx] = input[t0 * DIN + idx];
  float4 w[30];
  const float4* wr = (const float4*)(Wih0 + (size_t)tid * DIN);
#pragma unroll
  for (int i = 0; i < 30; ++i) w[i] = wr[i];
  float b = bih0[tid] + bhh0[tid];
  __syncthreads();
#pragma unroll
  for (int tt = 0; tt < 8; ++tt) {
    const float4* x4 = (const float4*)(xin + tt * DIN);
    float acc = b;
#pragma unroll
    for (int i = 0; i < 30; ++i) {
      float4 x = x4[i];
      acc += w[i].x * x.x + w[i].y * x.y + w[i].z * x.z + w[i].w * x.w;
    }
    ws[OFF_PRE0 + (t0 + tt) * G4 + un * 4 + grp] = acc;  // unit-major
  }
}

// ---------------- sequential scan: MFMA matvec, 16-step blocks, NO global ops in inner loop ----------------
// 512 thr / 8 waves. Waves 0-3: layer0; waves 4-7: layer1 (lag 1 superstep).
// PRE0 double-buffer-staged through LDS (refill loads issued 16 steps early);
// ACT/H/C staged in LDS, flushed per block with fire-and-forget float4 stores.
__global__ __launch_bounds__(512, 2) void wl_scan_kernel(const float* __restrict__ Whh0,
                                                         const float* __restrict__ Wih1,
                                                         const float* __restrict__ Whh1,
                                                         const float* __restrict__ bih1,
                                                         const float* __restrict__ bhh1,
                                                         float* __restrict__ ws) {
  __shared__ __align__(16) _Float16 h0h[2][HID];     // [buf][unit]
  __shared__ __align__(16) _Float16 h1h[2][HID];
  __shared__ __align__(16) float pre_stage[2][16 * G4];  // 32 KB
  __shared__ __align__(16) float sA0[16 * G4];           // 16 KB
  __shared__ __align__(16) float sA1[16 * G4];           // 16 KB
  __shared__ __align__(16) float sHC[4][16 * HID];       // 16 KB: H0 | C0 | H1 | C1
  float* ACT0 = ws + OFF_ACT0;
  float* ACT1 = ws + OFF_ACT1;
  float* H0S = ws + OFF_H0S;
  float* C0S = ws + OFF_C0S;
  float* H1S = ws + OFF_H1S;
  float* C1S = ws + OFF_C1S;
  const float* PRE0 = ws + OFF_PRE0;

  int tid = threadIdx.x;
  int wv = tid >> 6;
  int lane = tid & 63;
  int urow = lane & 15;   // B-fragment row selector
  int kq = lane >> 4;     // k-chunk 0..3
  bool isL1 = (wv >= 4);
  int w = wv & 3;
  int gu = 16 * w + urow; // this lane's unit (meaningful for lane<16)

  // B-fragments: wfA = Whh0 (L0) or Wih1 (L1); wfB = Whh1 (L1 only)
  const float* WAp = isL1 ? Wih1 : Whh0;
  half8 wfA[4][2], wfB[4][2];
#pragma unroll
  for (int g = 0; g < 4; ++g) {
#pragma unroll
    for (int kh = 0; kh < 2; ++kh) {
      wfA[g][kh] = ldw_(WAp, g * 64 + 16 * w + urow, kh * 32 + kq * 8);
      if (isL1) wfB[g][kh] = ldw_(Whh1, g * 64 + 16 * w + urow, kh * 32 + kq * 8);
      else      wfB[g][kh] = half8{};
    }
  }
  // L1 bias (i,f,g,o of unit gu), valid for lanes<16
  float4 b1v;
  b1v.x = bih1[gu] + bhh1[gu];
  b1v.y = bih1[64 + gu] + bhh1[64 + gu];
  b1v.z = bih1[128 + gu] + bhh1[128 + gu];
  b1v.w = bih1[192 + gu] + bhh1[192 + gu];

  // init LDS h buffers and boundary rows of the global state arrays
  if (tid < 128) {
    ((_Float16*)h0h)[tid] = (_Float16)0;
    ((_Float16*)h1h)[tid] = (_Float16)0;
  }
  if (tid < HID) {
    H0S[tid] = 0.0f; C0S[tid] = 0.0f;
    H1S[tid] = 0.0f; H1S[HID + tid] = 0.0f;
    C1S[tid] = 0.0f; C1S[HID + tid] = 0.0f;
  }
  // pre-stage block 0
  {
    const float4* src = (const float4*)(PRE0 + tid * 8);
    *(float4*)&pre_stage[0][tid * 8] = src[0];
    *(float4*)&pre_stage[0][tid * 8 + 4] = src[1];
  }
  float cc = 0.0f;
  __syncthreads();

  const f32x4 zed = {0.f, 0.f, 0.f, 0.f};
  int buf = 0;
  for (int b = 0; b <= NBLK; ++b) {
    bool has_next = (b < NBLK);
    float4 r0 = make_float4(0.f, 0.f, 0.f, 0.f), r1 = r0;
    if (has_next) {  // issue block b+1's PRE refill loads NOW (16 steps of slack)
      const float4* src = (const float4*)(PRE0 + (size_t)(b + 1) * 16 * G4 + tid * 8);
      r0 = src[0]; r1 = src[1];
    }
    for (int j = 0; j < 16; ++j) {
      int s = 16 * b + j;
      int rb = j & 1, wb = rb ^ 1;
      if (!isL1) {
        if (s < S_LEN) {
          float4 pr = *(const float4*)&pre_stage[buf][j * G4 + gu * 4];
          const half8* hb = (const half8*)h0h[rb];
          half8 a0 = hb[kq];        // k = kq*8..+8
          half8 a1 = hb[4 + kq];    // k = 32+kq*8..+8
          f32x4 ai = MFMA16(a0, wfA[0][0], zed); ai = MFMA16(a1, wfA[0][1], ai);
          f32x4 af = MFMA16(a0, wfA[1][0], zed); af = MFMA16(a1, wfA[1][1], af);
          f32x4 ag = MFMA16(a0, wfA[2][0], zed); ag = MFMA16(a1, wfA[2][1], ag);
          f32x4 ao = MFMA16(a0, wfA[3][0], zed); ao = MFMA16(a1, wfA[3][1], ao);
          if (lane < 16) {
            float gi = sig_(ai[0] + pr.x);
            float gf = sig_(af[0] + pr.y);
            float gg = tanh_(ag[0] + pr.z);
            float go = sig_(ao[0] + pr.w);
            cc = gf * cc + gi * gg;
            float th = tanh_(cc);
            float h = go * th;
            sA0[j * G4 + gu] = gi;
            sA0[j * G4 + 64 + gu] = gf;
            sA0[j * G4 + 128 + gu] = gg;
            sA0[j * G4 + 192 + gu] = go;
            sHC[0][j * HID + gu] = h;
            sHC[1][j * HID + gu] = cc;
            h0h[wb][gu] = (_Float16)h;
          }
        }
      } else {
        if (s >= 1 && s <= S_LEN) {
          const half8* hb0 = (const half8*)h0h[rb];  // h0[t]
          const half8* hb1 = (const half8*)h1h[rb];  // h1[t-1]
          half8 a00 = hb0[kq], a01 = hb0[4 + kq];
          half8 a10 = hb1[kq], a11 = hb1[4 + kq];
          // depth-2 chains per gate, combined with a scalar add
          f32x4 xi = MFMA16(a00, wfA[0][0], zed); xi = MFMA16(a01, wfA[0][1], xi);
          f32x4 yi = MFMA16(a10, wfB[0][0], zed); yi = MFMA16(a11, wfB[0][1], yi);
          f32x4 xf = MFMA16(a00, wfA[1][0], zed); xf = MFMA16(a01, wfA[1][1], xf);
          f32x4 yf = MFMA16(a10, wfB[1][0], zed); yf = MFMA16(a11, wfB[1][1], yf);
          f32x4 xg = MFMA16(a00, wfA[2][0], zed); xg = MFMA16(a01, wfA[2][1], xg);
          f32x4 yg = MFMA16(a10, wfB[2][0], zed); yg = MFMA16(a11, wfB[2][1], yg);
          f32x4 xo = MFMA16(a00, wfA[3][0], zed); xo = MFMA16(a01, wfA[3][1], xo);
          f32x4 yo = MFMA16(a10, wfB[3][0], zed); yo = MFMA16(a11, wfB[3][1], yo);
          if (lane < 16) {
            float gi = sig_(xi[0] + yi[0] + b1v.x);
            float gf = sig_(xf[0] + yf[0] + b1v.y);
            float gg = tanh_(xg[0] + yg[0] + b1v.z);
            float go = sig_(xo[0] + yo[0] + b1v.w);
            cc = gf * cc + gi * gg;
            float th = tanh_(cc);
            float h = go * th;
            sA1[j * G4 + gu] = gi;
            sA1[j * G4 + 64 + gu] = gf;
            sA1[j * G4 + 128 + gu] = gg;
            sA1[j * G4 + 192 + gu] = go;
            sHC[2][j * HID + gu] = h;
            sHC[3][j * HID + gu] = cc;
            h1h[wb][gu] = (_Float16)h;
          }
        }
      }
      // one light barrier per superstep (LDS drained; no vmcnt)
      asm volatile("s_waitcnt lgkmcnt(0)" ::: "memory");
      __builtin_amdgcn_sched_barrier(0);
      __builtin_amdgcn_s_barrier();
      __builtin_amdgcn_sched_barrier(0);
    }
    // ---- block epilogue: refill write + staged flush (stores fire-and-forget) ----
    int nbuf = buf ^ 1;
    if (has_next) {
      *(float4*)&pre_stage[nbuf][tid * 8] = r0;
      *(float4*)&pre_stage[nbuf][tid * 8 + 4] = r1;
    }
    {
      int idx = tid * 8, slot = idx >> 8, c = idx & 255;
      int t0 = 16 * b + slot;
      if (t0 < S_LEN) {
        float4 v0 = *(float4*)&sA0[idx], v1 = *(float4*)&sA0[idx + 4];
        *(float4*)&ACT0[(size_t)t0 * G4 + c] = v0;
        *(float4*)&ACT0[(size_t)t0 * G4 + c + 4] = v1;
      }
      int t1 = t0 - 1;
      if (t1 >= 0 && t1 < S_LEN) {
        float4 v0 = *(float4*)&sA1[idx], v1 = *(float4*)&sA1[idx + 4];
        *(float4*)&ACT1[(size_t)t1 * G4 + c] = v0;
        *(float4*)&ACT1[(size_t)t1 * G4 + c + 4] = v1;
      }
      int a = tid >> 7, q2 = (tid & 127) * 8, sl2 = q2 >> 6, u = q2 & 63;
      int tb = 16 * b + sl2;
      int ro = tb + 1;  // row index for H0S/C0S (t0=tb) and H1S/C1S (t1=tb-1 -> t1+2=ro)
      bool val = (a < 2) ? (tb < S_LEN) : (tb >= 1 && tb <= S_LEN);
      if (val) {
        float* gp = (a == 0 ? H0S : a == 1 ? C0S : a == 2 ? H1S : C1S) + (size_t)ro * HID + u;
        float4 v0 = *(float4*)&sHC[a][q2], v1 = *(float4*)&sHC[a][q2 + 4];
        *(float4*)gp = v0;
        *(float4*)(gp + 4) = v1;
      }
    }
    asm volatile("s_waitcnt lgkmcnt(0)" ::: "memory");
    __builtin_amdgcn_sched_barrier(0);
    __builtin_amdgcn_s_barrier();
    __builtin_amdgcn_sched_barrier(0);
    buf ^= 1;
  }
}

// ---------------- per-t gradient (fully parallel; uses stored activations only) ----------------
__global__ __launch_bounds__(256) void wl_grad_kernel(const float* __restrict__ Wih0,
                                                      const float* __restrict__ Whh0,
                                                      const float* __restrict__ Wih1,
                                                      const float* __restrict__ Whh1,
                                                      float* __restrict__ ws) {
  int t = blockIdx.x;
  int tid = threadIdx.x;
  float* GOH = ws + OFF_GOH;
  float* GWS = ws + OFF_GWS;
  if (t == 0) {  // gohs[0]=0, gws[0]=0
    if (tid < HID) GOH[tid] = 0.0f;
    if (tid < DIN) GWS[tid] = 0.0f;
    return;
  }
  const float* ACT0 = ws + OFF_ACT0;
  const float* ACT1 = ws + OFF_ACT1;
  const float* C0S = ws + OFF_C0S;
  const float* C1S = ws + OFF_C1S;
  __shared__ float a3[G4], am[G4], a0[G4];
  __shared__ float dg3[G4], dg0[G4], dgm[G4];
  __shared__ float dh0n[HID], dh1m[HID], dc1m[HID];
  __shared__ float cbuf[5 * HID];  // c3 | c1m | c1pp | c0n | c0p
  __shared__ float wsum_s[HID];
  a3[tid] = ACT1[(size_t)t * G4 + tid];
  am[tid] = ACT1[(size_t)(t - 1) * G4 + tid];
  a0[tid] = ACT0[(size_t)t * G4 + tid];
  if (tid < HID) {
    cbuf[tid]           = C1S[(size_t)(t + 2) * HID + tid];  // c3  = c1[t]
    cbuf[HID + tid]     = C1S[(size_t)(t + 1) * HID + tid];  // c1m = c1[t-1]
    cbuf[2 * HID + tid] = C1S[(size_t)t * HID + tid];        // c1pp= c1[t-2]
    cbuf[3 * HID + tid] = C0S[(size_t)(t + 1) * HID + tid];  // c0n = c0[t]
    cbuf[4 * HID + tid] = C0S[(size_t)t * HID + tid];        // c0p = c0[t-1]
    wsum_s[tid] = ws[OFF_WSUM + tid];
  }
  __syncthreads();
  // backward through cell3 (== real layer-1 cell at step t)
  if (tid < HID) {
    int k = tid;
    float tc = tanh_(cbuf[k]);
    float si = a3[k], sf = a3[HID + k], tg = a3[2 * HID + k], so = a3[3 * HID + k];
    float dh = wsum_s[k];
    float dov = dh * tc * so * (1.0f - so);
    float dc = dh * so * (1.0f - tc * tc);
    dg3[k] = dc * tg * si * (1.0f - si);
    dg3[HID + k] = dc * cbuf[HID + k] * sf * (1.0f - sf);
    dg3[2 * HID + k] = dc * si * (1.0f - tg * tg);
    dg3[3 * HID + k] = dov;
    dc1m[k] = dc * sf;
  }
  __syncthreads();
  // dh0n = dg3 @ Wih1 ; dh1m = dg3 @ Whh1
  if (tid < HID) {
    float s = 0.0f;
#pragma unroll 8
    for (int j = 0; j < G4; ++j) s += dg3[j] * Wih1[(size_t)j * HID + tid];
    dh0n[tid] = s;
  } else if (tid < 2 * HID) {
    int k = tid - HID;
    float s = 0.0f;
#pragma unroll 8
    for (int j = 0; j < G4; ++j) s += dg3[j] * Whh1[(size_t)j * HID + k];
    dh1m[k] = s;
  }
  __syncthreads();
  // backward through cell0 (dc0n = 0) and cellm (== layer-1 cell at step t-1)
  if (tid < HID) {
    int k = tid;
    float tc = tanh_(cbuf[3 * HID + k]);
    float si = a0[k], sf = a0[HID + k], tg = a0[2 * HID + k], so = a0[3 * HID + k];
    float dh = dh0n[k];
    float dov = dh * tc * so * (1.0f - so);
    float dc = dh * so * (1.0f - tc * tc);
    dg0[k] = dc * tg * si * (1.0f - si);
    dg0[HID + k] = dc * cbuf[4 * HID + k] * sf * (1.0f - sf);
    dg0[2 * HID + k] = dc * si * (1.0f - tg * tg);
    dg0[3 * HID + k] = dov;
  } else if (tid < 2 * HID) {
    int k = tid - HID;
    float tc = tanh_(cbuf[HID + k]);
    float si = am[k], sf = am[HID + k], tg = am[2 * HID + k], so = am[3 * HID + k];
    float dh = dh1m[k];
    float dov = dh * tc * so * (1.0f - so);
    float dc = dh * so * (1.0f - tc * tc) + dc1m[k];
    dgm[k] = dc * tg * si * (1.0f - si);
    dgm[HID + k] = dc * cbuf[2 * HID + k] * sf * (1.0f - sf);
    dgm[2 * HID + k] = dc * si * (1.0f - tg * tg);
    dgm[3 * HID + k] = dov;
  }
  __syncthreads();
  // gws = dg0 @ Wih0 ; gohs = dg0 @ Whh0 + dgm @ Wih1
  if (tid < DIN) {
    float s = 0.0f;
#pragma unroll 8
    for (int j = 0; j < G4; ++j) s += dg0[j] * Wih0[(size_t)j * DIN + tid];
    GWS[(size_t)t * DIN + tid] = s;
  } else if (tid < DIN + HID) {
    int k = tid - DIN;
    float sA = 0.0f, sB = 0.0f;
#pragma unroll 8
    for (int j = 0; j < G4; ++j) {
      sA += dg0[j] * Whh0[(size_t)j * HID + k];
      sB += dgm[j] * Wih1[(size_t)j * HID + k];
    }
    GOH[(size_t)t * HID + k] = sA + sB;
  }
}

// ---------------- outs[t] = Wlin @ h1[t] + blin ----------------
__global__ __launch_bounds__(256) void wl_outs_kernel(const float* __restrict__ Wlin,
                                                      const float* __restrict__ blin,
                                                      const float* __restrict__ ws,
                                                      float* __restrict__ out) {
  int tloc = threadIdx.x >> 5, o = threadIdx.x & 31;
  int t = blockIdx.x * 8 + tloc;
  if (o < NOUT) {
    const float* h1 = ws + OFF_H1S + (size_t)(t + 2) * HID;
    const float* wr = Wlin + o * HID;
    float s = blin[o];
#pragma unroll 8
    for (int k = 0; k < HID; ++k) s += wr[k] * h1[k];
    out[(size_t)t * NOUT + o] = s;
  }
}

// ---------------- column-wise min/max partials for gohs (m=0) and old_hts (m=1) ----------------
__global__ __launch_bounds__(256) void wl_mm_partial_kernel(float* __restrict__ ws) {
  int m = blockIdx.y;
  int col = threadIdx.x & 63, rg = threadIdx.x >> 6;
  const float* src = ws + (m == 0 ? OFF_GOH : OFF_H0S);  // H0S rows 0..8191 == old_hts
  float mn = 3.4e38f, mx = -3.4e38f;
  int r0 = blockIdx.x * 128;
  for (int r = r0 + rg; r < r0 + 128; r += 4) {
    float v = src[(size_t)r * HID + col];
    mn = fminf(mn, v);
    mx = fmaxf(mx, v);
  }
  __shared__ float smn[256], smx[256];
  smn[threadIdx.x] = mn;
  smx[threadIdx.x] = mx;
  __syncthreads();
  if (threadIdx.x < 64) {
    float a = fminf(fminf(smn[col], smn[64 + col]), fminf(smn[128 + col], smn[192 + col]));
    float b = fmaxf(fmaxf(smx[col], smx[64 + col]), fmaxf(smx[128 + col], smx[192 + col]));
    ws[OFF_PMN + ((size_t)m * 64 + blockIdx.x) * 64 + col] = a;
    ws[OFF_PMX + ((size_t)m * 64 + blockIdx.x) * 64 + col] = b;
  }
}

__global__ __launch_bounds__(128) void wl_mm_final_kernel(float* __restrict__ ws) {
  int i = threadIdx.x;
  if (i < 128) {
    int m = i >> 6, col = i & 63;
    float mn = 3.4e38f, mx = -3.4e38f;
    for (int b = 0; b < 64; ++b) {
      mn = fminf(mn, ws[OFF_PMN + ((size_t)m * 64 + b) * 64 + col]);
      mx = fmaxf(mx, ws[OFF_PMX + ((size_t)m * 64 + b) * 64 + col]);
    }
    ws[OFF_MN + i] = mn;
    ws[OFF_INV + i] = 1.0f / (mx - mn + 1e-6f);
  }
}

// ---------------- final: output_data assembly + HPM fwd + F + AllF_x ----------------
__global__ __launch_bounds__(256) void wl_final_kernel(const float* __restrict__ input,
                                                       const float* __restrict__ Whpm1,
                                                       const float* __restrict__ bhpm1,
                                                       const float* __restrict__ Whpm2,
                                                       const float* __restrict__ bhpm2,
                                                       const float* __restrict__ ws,
                                                       float* __restrict__ out) {
  int t = blockIdx.x;
  int tid = threadIdx.x;
  __shared__ float od[DHPM];
  __shared__ float red[256];
  __shared__ float zb[4];
  const float* GOH = ws + OFF_GOH;
  const float* H0S = ws + OFF_H0S;
  const float* MNp = ws + OFF_MN;
  const float* INVp = ws + OFF_INV;
  if (tid < NOUT) {
    od[tid] = out[(size_t)t * NOUT + tid];
  } else if (tid < 74) {
    int k = tid - 10;
    od[tid] = (GOH[(size_t)t * HID + k] - MNp[k]) * INVp[k];
  } else if (tid < 194) {
    int q = tid - 74;
    od[tid] = input[(size_t)t * DIN + q];
  } else {
    int k = tid - 194;
    od[tid] = (H0S[(size_t)t * HID + k] - MNp[64 + k]) * INVp[64 + k];
  }
  if (tid < 2) {
    int k = 62 + tid;
    od[256 + tid] = (H0S[(size_t)t * HID + k] - MNp[64 + k]) * INVp[64 + k];
  }
  __syncthreads();
  // z1pre[0]
  float p = od[tid] * Whpm1[tid];
  if (tid < 2) p += od[256 + tid] * Whpm1[256 + tid];
  red[tid] = p;
  __syncthreads();
  for (int off = 128; off > 0; off >>= 1) {
    if (tid < off) red[tid] += red[tid + off];
    __syncthreads();
  }
  if (tid == 0) zb[0] = red[0];
  __syncthreads();
  // z1pre[1]
  p = od[tid] * Whpm1[DHPM + tid];
  if (tid < 2) p += od[256 + tid] * Whpm1[DHPM + 256 + tid];
  red[tid] = p;
  __syncthreads();
  for (int off = 128; off > 0; off >>= 1) {
    if (tid < off) red[tid] += red[tid + off];
    __syncthreads();
  }
  if (tid == 0) {
    float z0 = tanh_(zb[0] + bhpm1[0]);
    float z1 = tanh_(red[0] + bhpm1[1]);
    zb[0] = z0;
    zb[1] = z1;
    zb[2] = ws[OFF_S2 + 0] * (1.0f - z0 * z0);
    zb[3] = ws[OFF_S2 + 1] * (1.0f - z1 * z1);
  }
  __syncthreads();
  float z0 = zb[0], z1 = zb[1], d0 = zb[2], d1 = zb[3];
  if (tid < DIN) {
    float G = bhpm2[tid] + z0 * Whpm2[tid * 2] + z1 * Whpm2[tid * 2 + 1];
    out[(size_t)S_LEN * NOUT + (size_t)t * DIN + tid] = ws[OFF_GWS + (size_t)t * DIN + tid] - G;
  }
  out[(size_t)S_LEN * (NOUT + DIN) + (size_t)t * DHPM + tid] = -(d0 * Whpm1[tid] + d1 * Whpm1[DHPM + tid]);
  if (tid < 2) {
    int i2 = 256 + tid;
    out[(size_t)S_LEN * (NOUT + DIN) + (size_t)t * DHPM + i2] = -(d0 * Whpm1[i2] + d1 * Whpm1[DHPM + i2]);
  }
}

extern "C" void kernel_launch(void* const* d_in, const int* in_sizes, int n_in,
                              void* d_out, int out_size, void* d_ws, size_t ws_size,
                              hipStream_t stream) {
  const float* input = (const float*)d_in[0];
  const float* Wih0 = (const float*)d_in[1];
  const float* Whh0 = (const float*)d_in[2];
  const float* bih0 = (const float*)d_in[3];
  const float* bhh0 = (const float*)d_in[4];
  const float* Wih1 = (const float*)d_in[5];
  const float* Whh1 = (const float*)d_in[6];
  const float* bih1 = (const float*)d_in[7];
  const float* bhh1 = (const float*)d_in[8];
  const float* Wlin = (const float*)d_in[9];
  const float* blin = (const float*)d_in[10];
  const float* Whpm1 = (const float*)d_in[11];
  const float* bhpm1 = (const float*)d_in[12];
  const float* Whpm2 = (const float*)d_in[13];
  const float* bhpm2 = (const float*)d_in[14];
  float* ws = (float*)d_ws;
  float* out = (float*)d_out;

  wl_prep_kernel<<<1, 128, 0, stream>>>(Wlin, Whpm2, ws);
  wl_pre0_kernel<<<S_LEN / 8, 256, 0, stream>>>(input, Wih0, bih0, bhh0, ws);
  wl_scan_kernel<<<1, 512, 0, stream>>>(Whh0, Wih1, Whh1, bih1, bhh1, ws);
  wl_grad_kernel<<<S_LEN, 256, 0, stream>>>(Wih0, Whh0, Wih1, Whh1, ws);
  wl_outs_kernel<<<S_LEN / 8, 256, 0, stream>>>(Wlin, blin, ws, out);
  wl_mm_partial_kernel<<<dim3(64, 2), 256, 0, stream>>>(ws);
  wl_mm_final_kernel<<<1, 128, 0, stream>>>(ws);
  wl_final_kernel<<<S_LEN, 256, 0, stream>>>(input, Whpm1, bhpm1, Whpm2, bhpm2, ws, out);
}